// Round 5
// baseline (24133.522 us; speedup 1.0000x reference)
//
#include <hip/hip_runtime.h>
#include <hip/hip_cooperative_groups.h>
#include <math.h>

namespace cg = cooperative_groups;

#define NBLK 256
#define NTHR 512
#define HID  1024
#define NB   64
#define SEQL 256
#define VOC  2048
#define G4   4096

typedef __attribute__((ext_vector_type(8))) short bf16x8;
typedef __attribute__((ext_vector_type(4))) float f32x4;
typedef unsigned long long ULL;

__device__ __forceinline__ float sigm(float x) { return 1.0f / (1.0f + expf(-x)); }

// ============================ FAST PATH ============================
// ws layout (bytes):
//  P1: 128 tiles x 2 chunks x 64KB  = 16 MB   (W1 h-part, bf16 hi/lo, swizzled; block-private)
//  P2: 128 tiles x 4 chunks x 64KB  = 32 MB   (W2)
//  P3: 128 tiles x 4 chunks x 64KB  = 32 MB   (W3)
//  PY: 128 tiles x 2 chunks x 32KB  =  8 MB   (Wout)
//  H : 6 x (hi[64][1024] + lo[64][1024]) shorts = 1.5 MB  (cross-block: AGENT-scope 32/64-bit)
//  C : 3 x [1024][64] float = 768 KB          (block-private)
//  FLG: 256 x 16B barrier flags (flags[0] doubles as the release word)
#define OFF_P1 0u
#define OFF_P2 16777216u
#define OFF_P3 50331648u
#define OFF_PY 83886080u
#define OFF_H  92274688u
#define OFF_C  93847552u
#define OFF_FLG 94633984u
#define WS_NEED 94638080ull

struct SmemF {
    short bbuf[2][32768];   // 2 x 64KB weight-chunk images (hi 32KB + lo 32KB), swizzled
    float tile[64 * 33];    // reduced C tile
    f32x4 redA[8][64];      // cross-wave K reduce (cols 0-15 / y)
    f32x4 redB[8][64];      // cross-wave K reduce (cols 16-31)
    int   tok[64];
};                          // 156,160 B

union UB { ULL u[2]; bf16x8 v; };

// ---- centralized grid barrier: no contended RMW, no L2 invalidate ----
// Arrivals: block b>0 stores flags[b*4]=e (sc1). Block 0: lanes 1..255 poll one
// flag each, then tid0 publishes flags[0]=e. Blocks b>0: tid0 polls flags[0].
// Per-wave vmcnt drain BEFORE the block barrier so every wave's stores are
// complete before any arrival store is issued.
__device__ __forceinline__ void gbar(int* flags, int e) {
    asm volatile("s_waitcnt vmcnt(0) lgkmcnt(0)" ::: "memory");
    __syncthreads();
    if (blockIdx.x == 0) {
        const int t = threadIdx.x;
        if (t >= 1 && t < NBLK) {
            while ((int)((unsigned)__hip_atomic_load(&flags[t * 4], __ATOMIC_RELAXED,
                          __HIP_MEMORY_SCOPE_AGENT) - (unsigned)e) < 0)
                __builtin_amdgcn_s_sleep(8);
        }
        __syncthreads();
        if (t == 0)
            __hip_atomic_store(&flags[0], e, __ATOMIC_RELAXED, __HIP_MEMORY_SCOPE_AGENT);
    } else {
        if (threadIdx.x == 0) {
            __hip_atomic_store(&flags[blockIdx.x * 4], e, __ATOMIC_RELAXED,
                               __HIP_MEMORY_SCOPE_AGENT);
            while ((int)((unsigned)__hip_atomic_load(&flags[0], __ATOMIC_RELAXED,
                          __HIP_MEMORY_SCOPE_AGENT) - (unsigned)e) < 0)
                __builtin_amdgcn_s_sleep(8);
        }
        __syncthreads();
    }
}

// prepack one 64KB gate-chunk image (block-private; plain cached stores,
// made globally consistent by the single grid.sync after prepack).
__device__ void prepack_gate(uint32_t* __restrict__ img, const float* __restrict__ W,
                             int row0, int ta)
{
    for (int s = threadIdx.x; s < 16384; s += NTHR) {
        const int b4 = s * 4;
        const int plane = b4 >> 15;
        const int bb = b4 & 32767;
        const int L = bb >> 10;
        const int r = (bb & 1023) ^ ((L & 7) << 4);
        const int k = r >> 1;
        const int col = (L >> 3) * 1024 + ta * 8 + (L & 7);
        const float v0 = W[(size_t)(row0 + k) * G4 + col];
        const float v1 = W[(size_t)(row0 + k + 1) * G4 + col];
        uint32_t u;
        if (plane == 0) {
            u = (__float_as_uint(v0) >> 16) | (__float_as_uint(v1) & 0xFFFF0000u);
        } else {
            const float l0 = v0 - __uint_as_float(__float_as_uint(v0) & 0xFFFF0000u);
            const float l1 = v1 - __uint_as_float(__float_as_uint(v1) & 0xFFFF0000u);
            u = (__float_as_uint(l0) >> 16) | (__float_as_uint(l1) & 0xFFFF0000u);
        }
        img[s] = u;
    }
}

__device__ void prepack_y(uint32_t* __restrict__ img, const float* __restrict__ Wo,
                          int row0, int ty)
{
    for (int s = threadIdx.x; s < 8192; s += NTHR) {
        const int b4 = s * 4;
        const int plane = b4 >> 14;
        const int bb = b4 & 16383;
        const int L = bb >> 10;
        const int r = (bb & 1023) ^ ((L & 7) << 4);
        const int k = r >> 1;
        const int col = ty * 16 + L;
        const float v0 = Wo[(size_t)(row0 + k) * VOC + col];
        const float v1 = Wo[(size_t)(row0 + k + 1) * VOC + col];
        uint32_t u;
        if (plane == 0) {
            u = (__float_as_uint(v0) >> 16) | (__float_as_uint(v1) & 0xFFFF0000u);
        } else {
            const float l0 = v0 - __uint_as_float(__float_as_uint(v0) & 0xFFFF0000u);
            const float l1 = v1 - __uint_as_float(__float_as_uint(v1) & 0xFFFF0000u);
            u = (__float_as_uint(l0) >> 16) | (__float_as_uint(l1) & 0xFFFF0000u);
        }
        img[s] = u;
    }
}

// N=32 gate GEMM. wave = (mt 0..3, kh 0..1): K-split halves redundant A reads;
// each wave computes BOTH 16-col tiles. A loads are 64-bit AGENT-scope (MALL).
template<int NCH, bool TWOSEG>
__device__ __forceinline__ void gemm_gate(SmemF* sm, const char* __restrict__ pack,
    const short* __restrict__ A0, const short* __restrict__ A1)
{
    const int tid = threadIdx.x;
    const int w = tid >> 6, lane = tid & 63;
    const int mt = w >> 1, kh = w & 1;
    const int c16 = lane & 15, g = lane >> 4;
    const int swz = (c16 & 7) << 4;

    f32x4 acc0 = {0.f, 0.f, 0.f, 0.f}, acc1 = {0.f, 0.f, 0.f, 0.f};
    uint4 st[8];

    #pragma unroll
    for (int i = 0; i < 8; ++i)
        st[i] = *(const uint4*)(pack + (i * NTHR + tid) * 16);
    #pragma unroll
    for (int i = 0; i < 8; ++i)
        *(uint4*)((char*)sm->bbuf[0] + (i * NTHR + tid) * 16) = st[i];
    __syncthreads();

    #pragma unroll
    for (int ch = 0; ch < NCH; ++ch) {
        if (ch + 1 < NCH) {                      // prefetch next weight chunk (cached)
            const char* src = pack + (size_t)(ch + 1) * 65536;
            #pragma unroll
            for (int i = 0; i < 8; ++i)
                st[i] = *(const uint4*)(src + (i * NTHR + tid) * 16);
        }
        const short* Aseg = (TWOSEG && ch >= 2) ? A1 : A0;
        const int kk0 = (TWOSEG ? (ch & 1) : ch) * 512 + kh * 256;
        const short* ap = Aseg + (size_t)(mt * 16 + c16) * 1024 + kk0 + g * 8;
        ULL ahx[8][2], alx[8][2];
        #pragma unroll
        for (int ks = 0; ks < 8; ++ks) {
            const ULL* ph = (const ULL*)(ap + ks * 32);
            const ULL* pl = (const ULL*)(ap + 65536 + ks * 32);
            ahx[ks][0] = __hip_atomic_load(ph,     __ATOMIC_RELAXED, __HIP_MEMORY_SCOPE_AGENT);
            ahx[ks][1] = __hip_atomic_load(ph + 1, __ATOMIC_RELAXED, __HIP_MEMORY_SCOPE_AGENT);
            alx[ks][0] = __hip_atomic_load(pl,     __ATOMIC_RELAXED, __HIP_MEMORY_SCOPE_AGENT);
            alx[ks][1] = __hip_atomic_load(pl + 1, __ATOMIC_RELAXED, __HIP_MEMORY_SCOPE_AGENT);
        }
        const char* bb = (const char*)sm->bbuf[ch & 1];
        #pragma unroll
        for (int ks = 0; ks < 8; ++ks) {
            UB a_h, a_l;
            a_h.u[0] = ahx[ks][0]; a_h.u[1] = ahx[ks][1];
            a_l.u[0] = alx[ks][0]; a_l.u[1] = alx[ks][1];
            const int kb = kh * 512 + ks * 64 + g * 16;
            const int b0 = (c16 * 1024 + kb) ^ swz;
            const int b1 = ((16 + c16) * 1024 + kb) ^ swz;
            const bf16x8 bh0 = *(const bf16x8*)(bb + b0);
            const bf16x8 bl0 = *(const bf16x8*)(bb + 32768 + b0);
            const bf16x8 bh1 = *(const bf16x8*)(bb + b1);
            const bf16x8 bl1 = *(const bf16x8*)(bb + 32768 + b1);
            acc0 = __builtin_amdgcn_mfma_f32_16x16x32_bf16(a_h.v, bh0, acc0, 0, 0, 0);
            acc0 = __builtin_amdgcn_mfma_f32_16x16x32_bf16(a_l.v, bh0, acc0, 0, 0, 0);
            acc0 = __builtin_amdgcn_mfma_f32_16x16x32_bf16(a_h.v, bl0, acc0, 0, 0, 0);
            acc1 = __builtin_amdgcn_mfma_f32_16x16x32_bf16(a_h.v, bh1, acc1, 0, 0, 0);
            acc1 = __builtin_amdgcn_mfma_f32_16x16x32_bf16(a_l.v, bh1, acc1, 0, 0, 0);
            acc1 = __builtin_amdgcn_mfma_f32_16x16x32_bf16(a_h.v, bl1, acc1, 0, 0, 0);
        }
        if (ch + 1 < NCH) {
            #pragma unroll
            for (int i = 0; i < 8; ++i)
                *(uint4*)((char*)sm->bbuf[(ch + 1) & 1] + (i * NTHR + tid) * 16) = st[i];
        }
        __syncthreads();
    }

    sm->redA[w][lane] = acc0;
    sm->redB[w][lane] = acc1;
    __syncthreads();
    if (kh == 0) {
        const f32x4 o0 = sm->redA[w + 1][lane];
        const f32x4 o1 = sm->redB[w + 1][lane];
        #pragma unroll
        for (int i2 = 0; i2 < 4; ++i2) { acc0[i2] += o0[i2]; acc1[i2] += o1[i2]; }
        const int r0 = mt * 16 + g * 4;              // verified C/D layout (m89)
        #pragma unroll
        for (int i2 = 0; i2 < 4; ++i2) {
            sm->tile[(r0 + i2) * 33 + c16]      = acc0[i2];
            sm->tile[(r0 + i2) * 33 + 16 + c16] = acc1[i2];
        }
    }
    __syncthreads();
}

// y GEMM: N=16, wave = (mt, kh), reduce via redA.
__device__ __forceinline__ void gemm_y(SmemF* sm, const char* __restrict__ pack,
                                       const short* __restrict__ A0)
{
    const int tid = threadIdx.x;
    const int w = tid >> 6, lane = tid & 63;
    const int mt = w >> 1, kh = w & 1;
    const int c16 = lane & 15, g = lane >> 4;
    const int swz = (c16 & 7) << 4;

    f32x4 acc = {0.f, 0.f, 0.f, 0.f};
    uint4 st[4];
    #pragma unroll
    for (int i = 0; i < 4; ++i)
        st[i] = *(const uint4*)(pack + (i * NTHR + tid) * 16);
    #pragma unroll
    for (int i = 0; i < 4; ++i)
        *(uint4*)((char*)sm->bbuf[0] + (i * NTHR + tid) * 16) = st[i];
    __syncthreads();

    #pragma unroll
    for (int ch = 0; ch < 2; ++ch) {
        if (ch == 0) {
            const char* src = pack + 32768;
            #pragma unroll
            for (int i = 0; i < 4; ++i)
                st[i] = *(const uint4*)(src + (i * NTHR + tid) * 16);
        }
        const int kk0 = ch * 512 + kh * 256;
        const short* ap = A0 + (size_t)(mt * 16 + c16) * 1024 + kk0 + g * 8;
        ULL ahx[8][2], alx[8][2];
        #pragma unroll
        for (int ks = 0; ks < 8; ++ks) {
            const ULL* ph = (const ULL*)(ap + ks * 32);
            const ULL* pl = (const ULL*)(ap + 65536 + ks * 32);
            ahx[ks][0] = __hip_atomic_load(ph,     __ATOMIC_RELAXED, __HIP_MEMORY_SCOPE_AGENT);
            ahx[ks][1] = __hip_atomic_load(ph + 1, __ATOMIC_RELAXED, __HIP_MEMORY_SCOPE_AGENT);
            alx[ks][0] = __hip_atomic_load(pl,     __ATOMIC_RELAXED, __HIP_MEMORY_SCOPE_AGENT);
            alx[ks][1] = __hip_atomic_load(pl + 1, __ATOMIC_RELAXED, __HIP_MEMORY_SCOPE_AGENT);
        }
        const char* bb = (const char*)sm->bbuf[ch & 1];
        #pragma unroll
        for (int ks = 0; ks < 8; ++ks) {
            UB a_h, a_l;
            a_h.u[0] = ahx[ks][0]; a_h.u[1] = ahx[ks][1];
            a_l.u[0] = alx[ks][0]; a_l.u[1] = alx[ks][1];
            const int kb = kh * 512 + ks * 64 + g * 16;
            const int b0 = (c16 * 1024 + kb) ^ swz;
            const bf16x8 bh0 = *(const bf16x8*)(bb + b0);
            const bf16x8 bl0 = *(const bf16x8*)(bb + 16384 + b0);
            acc = __builtin_amdgcn_mfma_f32_16x16x32_bf16(a_h.v, bh0, acc, 0, 0, 0);
            acc = __builtin_amdgcn_mfma_f32_16x16x32_bf16(a_l.v, bh0, acc, 0, 0, 0);
            acc = __builtin_amdgcn_mfma_f32_16x16x32_bf16(a_h.v, bl0, acc, 0, 0, 0);
        }
        if (ch == 0) {
            #pragma unroll
            for (int i = 0; i < 4; ++i)
                *(uint4*)((char*)sm->bbuf[1] + (i * NTHR + tid) * 16) = st[i];
        }
        __syncthreads();
    }
    sm->redA[w][lane] = acc;
    __syncthreads();
}

// 256 threads: (m, up) -> hidden units 2up, 2up+1. H stores are paired 32-bit
// AGENT-scope stores (no 16-bit atomics anywhere).
__device__ __forceinline__ void gate_epi(SmemF* sm, const float* __restrict__ bias,
    const float* __restrict__ Wgather, float* __restrict__ cst,
    short* __restrict__ Hout, int ta)
{
    const int tid = threadIdx.x;
    if (tid < 256) {
        const int m = tid & 63, up = tid >> 6;
        const float* tl = sm->tile + m * 33;
        uint32_t hiw = 0, low = 0;
        #pragma unroll
        for (int q = 0; q < 2; ++q) {
            const int u = up * 2 + q;
            const int hb = ta * 8 + u;
            float f  = tl[u]      + bias[hb];
            float i  = tl[8 + u]  + bias[1024 + hb];
            float o  = tl[16 + u] + bias[2048 + hb];
            float ct = tl[24 + u] + bias[3072 + hb];
            if (Wgather) {                         // L1 one-hot row add (exact fp32)
                const float* wr = Wgather + (size_t)sm->tok[m] * G4 + hb;
                f += wr[0]; i += wr[1024]; o += wr[2048]; ct += wr[3072];
            }
            float* cp = cst + hb * 64 + m;         // block-private, cached
            const float cn = sigm(f) * (*cp) + sigm(i) * tanhf(ct);
            *cp = cn;
            const float h = sigm(o) * tanhf(cn);
            const uint32_t uh = __float_as_uint(h);
            const float lof = h - __uint_as_float(uh & 0xFFFF0000u);
            hiw |= (uh >> 16) << (16 * q);
            low |= (__float_as_uint(lof) >> 16) << (16 * q);
        }
        const int si = m * 1024 + ta * 8 + up * 2; // even short index -> 4B aligned
        __hip_atomic_store((uint32_t*)(Hout + si), hiw,
                           __ATOMIC_RELAXED, __HIP_MEMORY_SCOPE_AGENT);
        __hip_atomic_store((uint32_t*)(Hout + 65536 + si), low,
                           __ATOMIC_RELAXED, __HIP_MEMORY_SCOPE_AGENT);
    }
}

__device__ __forceinline__ void y_epi(SmemF* sm, int t, const float* __restrict__ bo,
                                      int vc0, float* __restrict__ out)
{
    const int tid = threadIdx.x;
    const int c = tid & 15, m0 = tid >> 4;
    #pragma unroll
    for (int hh = 0; hh < 2; ++hh) {
        const int m = m0 + hh * 32;
        const int mt = m >> 4, mr = m & 15;
        const int l = ((mr >> 2) << 4) | c;
        const int i = mr & 3;
        const float v = sm->redA[mt * 2][l][i] + sm->redA[mt * 2 + 1][l][i] + bo[vc0 + c];
        __builtin_nontemporal_store(v, out + ((size_t)t * NB + m) * VOC + vc0 + c);
    }
    __syncthreads();
}

__global__ __launch_bounds__(NTHR, 2) void lstm3_v5(
    const int*   __restrict__ X,
    const float* __restrict__ W1, const float* __restrict__ b1,
    const float* __restrict__ W2, const float* __restrict__ b2,
    const float* __restrict__ W3, const float* __restrict__ b3,
    const float* __restrict__ Wo, const float* __restrict__ bo,
    float* __restrict__ out, char* __restrict__ wsb)
{
    cg::grid_group grid = cg::this_grid();
    __shared__ SmemF sm;

    const int tid = threadIdx.x, blk = blockIdx.x;
    const bool grpA = blk < 128;
    const int bidx = grpA ? blk : blk - 128;
    const int ta = (bidx & 7) * 16 + (bidx >> 3);  // XCD-aware tile ownership (perf only)
    int* flags = (int*)(wsb + OFF_FLG);

    // zero own barrier flag (visibility via the grid.sync below)
    if (tid == 0)
        __hip_atomic_store(&flags[blk * 4], 0, __ATOMIC_RELAXED, __HIP_MEMORY_SCOPE_AGENT);

    // zero H + own C slice (plain stores; grid.sync makes them coherent)
    uint32_t* hz = (uint32_t*)(wsb + OFF_H);
    for (int i = blk * NTHR + tid; i < 393216; i += NBLK * NTHR) hz[i] = 0u;
    float* C = (float*)(wsb + OFF_C);
    if (grpA) {
        for (int i = tid; i < 512; i += NTHR) {
            C[ta * 512 + i] = 0.f;
            C[2 * 65536 + ta * 512 + i] = 0.f;
        }
    } else {
        for (int i = tid; i < 512; i += NTHR)
            C[65536 + ta * 512 + i] = 0.f;
    }

    // prepack own weight tiles (block-private images, plain cached stores)
    if (grpA) {
        for (int ch = 0; ch < 2; ++ch)
            prepack_gate((uint32_t*)(wsb + OFF_P1 + (size_t)ta * 131072 + ch * 65536),
                         W1, VOC + ch * 512, ta);
        for (int ch = 0; ch < 4; ++ch)
            prepack_gate((uint32_t*)(wsb + OFF_P3 + (size_t)ta * 262144 + ch * 65536),
                         W3, ch * 512, ta);
    } else {
        for (int ch = 0; ch < 4; ++ch)
            prepack_gate((uint32_t*)(wsb + OFF_P2 + (size_t)ta * 262144 + ch * 65536),
                         W2, ch * 512, ta);
        for (int ch = 0; ch < 2; ++ch)
            prepack_y((uint32_t*)(wsb + OFF_PY + (size_t)ta * 65536 + ch * 32768),
                      Wo, ch * 512, ta);
    }
    // the ONE heavy sync: publishes prepack + zeroed flags/H/C everywhere
    grid.sync();

    short* H = (short*)(wsb + OFF_H);
    #define HP(l_, s_) (H + ((l_) * 2 + (s_)) * 131072)

    // Diagonal pipeline: superstep s: grpA runs L1(t=s) & L3(s-2); grpB runs
    // L2(s-1) & y(s-3). One flag barrier per superstep (epochs 1..259).
    for (int s = 0; s <= SEQL + 2; ++s) {
        if (tid < 64 && s < SEQL) sm.tok[tid] = X[tid * SEQL + s];

        if (grpA) {
            if (s < SEQL) {
                const int sl = s & 1;
                gemm_gate<2, false>(&sm, wsb + OFF_P1 + (size_t)ta * 131072,
                                    HP(0, sl ^ 1), nullptr);
                gate_epi(&sm, b1, W1, C, HP(0, sl), ta);
            }
            if (s >= 2 && s <= SEQL + 1) {
                const int t = s - 2, sl = t & 1;
                gemm_gate<4, true>(&sm, wsb + OFF_P3 + (size_t)ta * 262144,
                                   HP(1, sl), HP(2, sl ^ 1));
                gate_epi(&sm, b3, nullptr, C + 2 * 65536, HP(2, sl), ta);
            }
        } else {
            if (s >= 1 && s <= SEQL) {
                const int t = s - 1, sl = t & 1;
                gemm_gate<4, true>(&sm, wsb + OFF_P2 + (size_t)ta * 262144,
                                   HP(0, sl), HP(1, sl ^ 1));
                gate_epi(&sm, b2, nullptr, C + 65536, HP(1, sl), ta);
            }
            if (s >= 3) {
                const int t = s - 3, sl = t & 1;
                gemm_y(&sm, wsb + OFF_PY + (size_t)ta * 65536, HP(2, sl));
                y_epi(&sm, t, bo, ta * 16, out);
            }
        }
        gbar(flags, s + 1);
    }

    // final states (h1,c1,h2,c2,h3,c3), each [64][1024]; t=255 -> slot 1
    if (tid < 256) {
        const int m = tid & 63, up = tid >> 6;
        const size_t base = (size_t)SEQL * NB * VOC;
        const size_t si = (size_t)m * 1024 + ta * 8 + up * 2;
        const int cu = (ta * 8 + up * 2) * 64 + m;
        #pragma unroll
        for (int pick = 0; pick < 2; ++pick) {
            const int lyr = grpA ? (pick ? 2 : 0) : 1;
            if (!grpA && pick) break;
            const short* hp = HP(lyr, 1);
            const uint32_t hw = __hip_atomic_load((const uint32_t*)(hp + si),
                                  __ATOMIC_RELAXED, __HIP_MEMORY_SCOPE_AGENT);
            const uint32_t lw = __hip_atomic_load((const uint32_t*)(hp + 65536 + si),
                                  __ATOMIC_RELAXED, __HIP_MEMORY_SCOPE_AGENT);
            const size_t ob = base + (size_t)(2 * lyr) * 65536 + si;
            out[ob]     = __uint_as_float((hw & 0xFFFFu) << 16)
                        + __uint_as_float((lw & 0xFFFFu) << 16);
            out[ob + 1] = __uint_as_float(hw & 0xFFFF0000u)
                        + __uint_as_float(lw & 0xFFFF0000u);
            const float* Cl = C + lyr * 65536;
            out[base + (size_t)(2 * lyr + 1) * 65536 + si]     = Cl[cu];
            out[base + (size_t)(2 * lyr + 1) * 65536 + si + 1] = Cl[cu + 64];
        }
    }
    #undef HP
}

// ============================ FALLBACK (round-2, used if ws too small) ============================
#define STG_STRIDE 520

struct SmemFB {
    short stg_hi[16 * STG_STRIDE];
    short stg_lo[16 * STG_STRIDE];
    f32x4 red[8][64];
    float tile[64 * 17];
    float cst[3 * 4 * 64];
    int   tok[64];
};

template<int KTOT, int MTILES>
__device__ void fb_gemm(SmemFB* sm, const float* __restrict__ W, int ldw, int wrow0,
                        const short* __restrict__ Ahi0, const short* __restrict__ Alo0,
                        const short* __restrict__ Ahi1, const short* __restrict__ Alo1,
                        bool gatecols, int cb, int mbase)
{
    constexpr int WPM = 8 / MTILES;
    constexpr int RPW = 512 / WPM;
    constexpr int KS  = RPW / 32;
    constexpr int NCH = KTOT / 512;

    const int tid = threadIdx.x;
    const int l   = tid & 63, w = tid >> 6;
    const int c16 = l & 15,  g = l >> 4;
    const int mt  = w / WPM, sub = w % WPM;
    const int sg  = tid & 3, kp  = tid >> 2;
    const int gc  = gatecols ? (sg * HID + cb) : (cb + sg * 4);

    f32x4 acc = {0.f, 0.f, 0.f, 0.f};

    for (int ch = 0; ch < NCH; ++ch) {
        #pragma unroll
        for (int rep = 0; rep < 2; ++rep) {
            const int kpair = kp + rep * 128;
            const int row   = wrow0 + ch * 512 + kpair * 2;
            const float4 w0 = *(const float4*)(W + (size_t)row * ldw + gc);
            const float4 w1 = *(const float4*)(W + (size_t)(row + 1) * ldw + gc);
            const float* a = (const float*)&w0;
            const float* b = (const float*)&w1;
            #pragma unroll
            for (int c = 0; c < 4; ++c) {
                const uint32_t ua = __float_as_uint(a[c]);
                const uint32_t ub = __float_as_uint(b[c]);
                const uint32_t hi = (ub & 0xFFFF0000u) | (ua >> 16);
                const float la = a[c] - __uint_as_float(ua & 0xFFFF0000u);
                const float lb = b[c] - __uint_as_float(ub & 0xFFFF0000u);
                const uint32_t lo = (__float_as_uint(lb) & 0xFFFF0000u)
                                  | (__float_as_uint(la) >> 16);
                const int off = (sg * 4 + c) * STG_STRIDE + kpair * 2;
                *(uint32_t*)&sm->stg_hi[off] = hi;
                *(uint32_t*)&sm->stg_lo[off] = lo;
            }
        }
        __syncthreads();

        const int kglob0 = ch * 512;
        const short* ahi = (KTOT == 2048 && kglob0 >= 1024) ? Ahi1 : Ahi0;
        const short* alo = (KTOT == 2048 && kglob0 >= 1024) ? Alo1 : Alo0;
        const int kk0 = kglob0 & 1023;
        const size_t arow = (size_t)(mbase + mt * 16 + c16) * HID;
        const short* ah = ahi + arow + kk0 + sub * RPW + g * 8;
        const short* al = alo + arow + kk0 + sub * RPW + g * 8;
        const short* bh = sm->stg_hi + c16 * STG_STRIDE + sub * RPW + g * 8;
        const short* bl = sm->stg_lo + c16 * STG_STRIDE + sub * RPW + g * 8;
        #pragma unroll
        for (int ks = 0; ks < KS; ++ks) {
            const bf16x8 a_hi = *(const bf16x8*)(ah + ks * 32);
            const bf16x8 a_lo = *(const bf16x8*)(al + ks * 32);
            const bf16x8 b_hi = *(const bf16x8*)(bh + ks * 32);
            const bf16x8 b_lo = *(const bf16x8*)(bl + ks * 32);
            acc = __builtin_amdgcn_mfma_f32_16x16x32_bf16(a_hi, b_hi, acc, 0, 0, 0);
            acc = __builtin_amdgcn_mfma_f32_16x16x32_bf16(a_lo, b_hi, acc, 0, 0, 0);
            acc = __builtin_amdgcn_mfma_f32_16x16x32_bf16(a_hi, b_lo, acc, 0, 0, 0);
        }
        __syncthreads();
    }

    sm->red[w][l] = acc;
    __syncthreads();
    if (sub == 0) {
        #pragma unroll
        for (int j = 1; j < WPM; ++j) {
            const f32x4 o = sm->red[w + j][l];
            acc[0] += o[0]; acc[1] += o[1]; acc[2] += o[2]; acc[3] += o[3];
        }
        const int r0 = mt * 16 + (l >> 4) * 4;
        sm->tile[(r0 + 0) * 17 + c16] = acc[0];
        sm->tile[(r0 + 1) * 17 + c16] = acc[1];
        sm->tile[(r0 + 2) * 17 + c16] = acc[2];
        sm->tile[(r0 + 3) * 17 + c16] = acc[3];
    }
    __syncthreads();
}

__device__ void fb_gate_epi(SmemFB* sm, int layer, const float* __restrict__ bias,
                            const float* __restrict__ W1gather, int hjb,
                            short* __restrict__ Hhi, short* __restrict__ Hlo)
{
    const int tid = threadIdx.x;
    if (tid < 256) {
        const int m = tid & 63, dh = tid >> 6;
        float f  = sm->tile[m * 17 + dh]       + bias[hjb + dh];
        float i  = sm->tile[m * 17 + 4 + dh]   + bias[HID + hjb + dh];
        float o  = sm->tile[m * 17 + 8 + dh]   + bias[2 * HID + hjb + dh];
        float ct = sm->tile[m * 17 + 12 + dh]  + bias[3 * HID + hjb + dh];
        if (W1gather) {
            const float* wr = W1gather + (size_t)sm->tok[m] * G4 + hjb + dh;
            f += wr[0]; i += wr[HID]; o += wr[2 * HID]; ct += wr[3 * HID];
        }
        const int ci = (layer * 4 + dh) * 64 + m;
        const float cn = sigm(f) * sm->cst[ci] + sigm(i) * tanhf(ct);
        sm->cst[ci] = cn;
        const float h = sigm(o) * tanhf(cn);
        const uint32_t uh = __float_as_uint(h);
        const float hiF = __uint_as_float(uh & 0xFFFF0000u);
        const float loV = h - hiF;
        const size_t idx = (size_t)m * HID + hjb + dh;
        Hhi[idx] = (short)(uh >> 16);
        Hlo[idx] = (short)(__float_as_uint(loV) >> 16);
    }
}

__device__ void fb_y_epi(SmemFB* sm, int t, const float* __restrict__ bo,
                         int vc0, int mh, float* __restrict__ out)
{
    const int tid = threadIdx.x;
    const int mloc = tid >> 4, c = tid & 15;
    const float v = sm->tile[mloc * 17 + c] + bo[vc0 + c];
    const int m = mh * 32 + mloc;
    __builtin_nontemporal_store(v, out + ((size_t)t * NB + m) * VOC + vc0 + c);
}

__global__ __launch_bounds__(NTHR, 1) void lstm3_fb(
    const int*   __restrict__ X,
    const float* __restrict__ W1, const float* __restrict__ b1,
    const float* __restrict__ W2, const float* __restrict__ b2,
    const float* __restrict__ W3, const float* __restrict__ b3,
    const float* __restrict__ Wo, const float* __restrict__ bo,
    float* __restrict__ out, short* __restrict__ hws)
{
    cg::grid_group grid = cg::this_grid();
    __shared__ SmemFB sm;

    const int tid = threadIdx.x;
    const int blk = blockIdx.x;
    const int tile = (blk & 7) * 32 + (blk >> 3);
    const int hjb  = tile * 4;
    const int q    = blk >> 3;
    const int ytile = (blk & 7) * 16 + (q & 15);
    const int mh    = q >> 4;
    const int vc0   = ytile * 16;

    uint32_t* wz = (uint32_t*)hws;
    for (int i = blk * NTHR + tid; i < 6 * 65536; i += NBLK * NTHR) wz[i] = 0u;
    for (int i = tid; i < 768; i += NTHR) sm.cst[i] = 0.f;
    grid.sync();

    #define HHI(l_, s_) (hws + ((l_) * 2 + (s_)) * 131072)
    #define HLO(l_, s_) (hws + ((l_) * 2 + (s_)) * 131072 + 65536)

    for (int s = 0; s <= SEQL + 2; ++s) {
        if (s < SEQL && tid < 64) sm.tok[tid] = X[tid * SEQL + s];

        if (s < SEQL) {
            const int t = s, sl = t & 1, sp = sl ^ 1;
            fb_gemm<1024, 4>(&sm, W1, G4, VOC, HHI(0, sp), HLO(0, sp),
                             nullptr, nullptr, true, hjb, 0);
            fb_gate_epi(&sm, 0, b1, W1, hjb, HHI(0, sl), HLO(0, sl));
        }
        if (s >= 1 && s <= SEQL) {
            const int t = s - 1, sl = t & 1, sp = sl ^ 1;
            fb_gemm<2048, 4>(&sm, W2, G4, 0, HHI(0, sl), HLO(0, sl),
                             HHI(1, sp), HLO(1, sp), true, hjb, 0);
            fb_gate_epi(&sm, 1, b2, nullptr, hjb, HHI(1, sl), HLO(1, sl));
        }
        if (s >= 2 && s <= SEQL + 1) {
            const int t = s - 2, sl = t & 1, sp = sl ^ 1;
            fb_gemm<2048, 4>(&sm, W3, G4, 0, HHI(1, sl), HLO(1, sl),
                             HHI(2, sp), HLO(2, sp), true, hjb, 0);
            fb_gate_epi(&sm, 2, b3, nullptr, hjb, HHI(2, sl), HLO(2, sl));
        }
        if (s >= 3) {
            const int t = s - 3, sl = t & 1;
            fb_gemm<1024, 2>(&sm, Wo, VOC, 0, HHI(2, sl), HLO(2, sl),
                             nullptr, nullptr, false, vc0, mh * 32);
            fb_y_epi(&sm, t, bo, vc0, mh, out);
        }
        grid.sync();
    }

    if (tid < 256) {
        const int m = tid & 63, dh = tid >> 6;
        const size_t base = (size_t)SEQL * NB * VOC;
        #pragma unroll
        for (int lyr = 0; lyr < 3; ++lyr) {
            const short* hh = HHI(lyr, 1);
            const short* hl = HLO(lyr, 1);
            const size_t idx = (size_t)m * HID + hjb + dh;
            const float h = __uint_as_float(((uint32_t)(uint16_t)hh[idx]) << 16)
                          + __uint_as_float(((uint32_t)(uint16_t)hl[idx]) << 16);
            out[base + (size_t)(2 * lyr) * 65536 + idx] = h;
            out[base + (size_t)(2 * lyr + 1) * 65536 + idx] =
                sm.cst[(lyr * 4 + dh) * 64 + m];
        }
    }
    #undef HHI
    #undef HLO
}

extern "C" void kernel_launch(void* const* d_in, const int* in_sizes, int n_in,
                              void* d_out, int out_size, void* d_ws, size_t ws_size,
                              hipStream_t stream)
{
    const int*   X  = (const int*)  d_in[0];
    const float* W1 = (const float*)d_in[1];
    const float* b1 = (const float*)d_in[2];
    const float* W2 = (const float*)d_in[3];
    const float* b2 = (const float*)d_in[4];
    const float* W3 = (const float*)d_in[5];
    const float* b3 = (const float*)d_in[6];
    const float* Wo = (const float*)d_in[7];
    const float* bo = (const float*)d_in[8];
    float* out = (float*)d_out;

    if (ws_size >= WS_NEED) {
        char* wsb = (char*)d_ws;
        void* args[] = { &X, &W1, &b1, &W2, &b2, &W3, &b3, &Wo, &bo, &out, &wsb };
        hipLaunchCooperativeKernel((const void*)lstm3_v5,
                                   dim3(NBLK), dim3(NTHR), args, 0, stream);
    } else {
        short* hws = (short*)d_ws;
        void* args[] = { &X, &W1, &b1, &W2, &b2, &W3, &b3, &Wo, &bo, &out, &hws };
        hipLaunchCooperativeKernel((const void*)lstm3_fb,
                                   dim3(NBLK), dim3(NTHR), args, 0, stream);
    }
}